// Round 16
// baseline (290.580 us; speedup 1.0000x reference)
//
#include <hip/hip_runtime.h>
#include <hip/hip_bf16.h>
#include <math.h>

#define D_MODEL 1024
#define H_NUM 16
#define HD 64
#define FF_DIM 2048
#define SEQ 2048
#define BATCH 4
#define M_TOK 8192  // BATCH*SEQ

typedef __attribute__((ext_vector_type(8))) short bf16x8;
typedef __attribute__((ext_vector_type(4))) float f32x4;
typedef __attribute__((ext_vector_type(16))) float f32x16;
typedef __attribute__((ext_vector_type(4))) unsigned int uint4v;
typedef __attribute__((ext_vector_type(2))) int int2v;

__device__ __forceinline__ short f2bf(float f) {
  __hip_bfloat16 h = __float2bfloat16(f);
  return *reinterpret_cast<short*>(&h);
}

__device__ __forceinline__ void gload16(const void* g, void* l) {
  __builtin_amdgcn_global_load_lds((const __attribute__((address_space(1))) void*)g,
                                   (__attribute__((address_space(3))) void*)l, 16, 0, 0);
}

__device__ __forceinline__ unsigned cvt_pk_bf16(float lo, float hi) {
  unsigned r;
  asm("v_cvt_pk_bf16_f32 %0, %1, %2" : "=v"(r) : "v"(lo), "v"(hi));
  return r;
}

// raw v_exp_f32 (2^x). Args bounded; tiny args flush to 0 (fine for softmax).
__device__ __forceinline__ float fexp2(float x) {
  float r;
  asm("v_exp_f32 %0, %1" : "=v"(r) : "v"(x));
  return r;
}

__device__ __forceinline__ float frcp(float x) {
  float r;
  asm("v_rcp_f32 %0, %1" : "=v"(r) : "v"(x));
  return r;
}

#define BARRIER() __builtin_amdgcn_s_barrier()
#define VMC(n)                                   \
  do {                                           \
    asm volatile("s_waitcnt vmcnt(" #n ")");     \
    __builtin_amdgcn_sched_barrier(0);           \
  } while (0)

// ---------------- fused: LN1 (bid < 8192) + all weight transposes (rest)
__global__ __launch_bounds__(256) void prep_fused(
    const float* __restrict__ x, const float* __restrict__ g1,
    const float* __restrict__ b1, short* __restrict__ xn,
    const float* __restrict__ Wq, const float* __restrict__ Wk,
    const float* __restrict__ Wv, const float* __restrict__ Wo,
    const float* __restrict__ W1, const float* __restrict__ W2,
    short* __restrict__ WqkvT, short* __restrict__ WoT,
    short* __restrict__ W1T, short* __restrict__ W2T) {
  __shared__ float tile[64][65];
  if (blockIdx.x < M_TOK) {
    // LayerNorm row
    const int row = blockIdx.x;
    const int t = threadIdx.x;
    const float* xr = x + (size_t)row * D_MODEL;
    float4 v = *(const float4*)(xr + t * 4);
    float s = v.x + v.y + v.z + v.w;
    float s2 = v.x * v.x + v.y * v.y + v.z * v.z + v.w * v.w;
#pragma unroll
    for (int m = 1; m < 64; m <<= 1) { s += __shfl_xor(s, m); s2 += __shfl_xor(s2, m); }
    float* ps = &tile[0][0];
    const int wid = t >> 6, lane = t & 63;
    if (lane == 0) { ps[wid] = s; ps[wid + 4] = s2; }
    __syncthreads();
    s = ps[0] + ps[1] + ps[2] + ps[3];
    s2 = ps[4] + ps[5] + ps[6] + ps[7];
    float mu = s * (1.f / D_MODEL);
    float rstd = rsqrtf(s2 * (1.f / D_MODEL) - mu * mu + 1e-5f);
    float4 gv = *(const float4*)(g1 + t * 4);
    float4 bv = *(const float4*)(b1 + t * 4);
    short4 o;
    o.x = f2bf((v.x - mu) * rstd * gv.x + bv.x);
    o.y = f2bf((v.y - mu) * rstd * gv.y + bv.y);
    o.z = f2bf((v.z - mu) * rstd * gv.z + bv.z);
    o.w = f2bf((v.w - mu) * rstd * gv.w + bv.w);
    *(short4*)(xn + (size_t)row * D_MODEL + t * 4) = o;
    return;
  }
  const int bid = blockIdx.x - M_TOK;
  const float* src;
  short* dst;
  int K, N, t;
  if (bid < 256)       { src = Wq; dst = WqkvT;           K = 1024; N = 1024; t = bid; }
  else if (bid < 512)  { src = Wk; dst = WqkvT + 1048576; K = 1024; N = 1024; t = bid - 256; }
  else if (bid < 768)  { src = Wv; dst = WqkvT + 2097152; K = 1024; N = 1024; t = bid - 512; }
  else if (bid < 1024) { src = Wo; dst = WoT;             K = 1024; N = 1024; t = bid - 768; }
  else if (bid < 1536) { src = W1; dst = W1T;             K = 1024; N = 2048; t = bid - 1024; }
  else                 { src = W2; dst = W2T;             K = 2048; N = 1024; t = bid - 1536; }
  const int lg = (N == 2048) ? 5 : 4;
  const int ty = t >> lg, tx = t & ((1 << lg) - 1);
  const int n0 = tx * 64, k0 = ty * 64;
  const int tr = threadIdx.x >> 4;
  const int tc = (threadIdx.x & 15) * 4;
#pragma unroll
  for (int i = 0; i < 4; ++i) {
    int kr = tr + i * 16;
    float4 v = *(const float4*)(src + (size_t)(k0 + kr) * N + n0 + tc);
    tile[kr][tc] = v.x; tile[kr][tc + 1] = v.y; tile[kr][tc + 2] = v.z; tile[kr][tc + 3] = v.w;
  }
  __syncthreads();
#pragma unroll
  for (int i = 0; i < 4; ++i) {
    int r = tr + i * 16;
    short4 o;
    o.x = f2bf(tile[tc][r]);
    o.y = f2bf(tile[tc + 1][r]);
    o.z = f2bf(tile[tc + 2][r]);
    o.w = f2bf(tile[tc + 3][r]);
    *(short4*)(dst + (size_t)(n0 + r) * K + k0 + tc) = o;
  }
}

// ---------------- V transpose: [BH][SEQ][HD] bf16 -> [BH][HD][SEQ]
__global__ __launch_bounds__(256) void transpose_v(const short* __restrict__ src,
                                                   short* __restrict__ dst) {
  __shared__ short t[64][72];
  const int s0 = blockIdx.x * 64;
  const size_t b = (size_t)blockIdx.y * SEQ * HD;
  const int r = threadIdx.x >> 2;          // seq row 0..63
  const int c = (threadIdx.x & 3) * 16;    // d col 0/16/32/48
  *(bf16x8*)&t[r][c] = *(const bf16x8*)(src + b + (size_t)(s0 + r) * HD + c);
  *(bf16x8*)&t[r][c + 8] = *(const bf16x8*)(src + b + (size_t)(s0 + r) * HD + c + 8);
  __syncthreads();
  const int d = threadIdx.x >> 2;          // d row 0..63
  const int cc = (threadIdx.x & 3) * 16;   // seq chunk
  bf16x8 o0, o1;
#pragma unroll
  for (int i = 0; i < 8; ++i) o0[i] = t[cc + i][d];
#pragma unroll
  for (int i = 0; i < 8; ++i) o1[i] = t[cc + 8 + i][d];
  *(bf16x8*)(dst + b + (size_t)d * SEQ + s0 + cc) = o0;
  *(bf16x8*)(dst + b + (size_t)d * SEQ + s0 + cc + 8) = o1;
}

// ---------------- LayerNorm fp32 [rows][1024] -> bf16, one block per row
__global__ __launch_bounds__(256) void ln_bf16(const float* __restrict__ x,
                                               const float* __restrict__ g,
                                               const float* __restrict__ b,
                                               short* __restrict__ out) {
  const int row = blockIdx.x;
  const int t = threadIdx.x;
  const float* xr = x + (size_t)row * D_MODEL;
  float4 v = *(const float4*)(xr + t * 4);
  float s = v.x + v.y + v.z + v.w;
  float s2 = v.x * v.x + v.y * v.y + v.z * v.z + v.w * v.w;
#pragma unroll
  for (int m = 1; m < 64; m <<= 1) { s += __shfl_xor(s, m); s2 += __shfl_xor(s2, m); }
  __shared__ float ps[8];
  const int wid = t >> 6, lane = t & 63;
  if (lane == 0) { ps[wid] = s; ps[wid + 4] = s2; }
  __syncthreads();
  s = ps[0] + ps[1] + ps[2] + ps[3];
  s2 = ps[4] + ps[5] + ps[6] + ps[7];
  float mu = s * (1.f / D_MODEL);
  float rstd = rsqrtf(s2 * (1.f / D_MODEL) - mu * mu + 1e-5f);
  float4 gv = *(const float4*)(g + t * 4);
  float4 bv = *(const float4*)(b + t * 4);
  short4 o;
  o.x = f2bf((v.x - mu) * rstd * gv.x + bv.x);
  o.y = f2bf((v.y - mu) * rstd * gv.y + bv.y);
  o.z = f2bf((v.z - mu) * rstd * gv.z + bv.z);
  o.w = f2bf((v.w - mu) * rstd * gv.w + bv.w);
  *(short4*)(out + (size_t)row * D_MODEL + t * 4) = o;
}

// ---------------- shared GEMM epilogue (NB = B frags per wave)
template <int FM, int NB, int MODE>
__device__ __forceinline__ void gemm_epilogue(f32x4 (&acc)[FM][NB], int row0, int col0,
                                              int wr, int wc, int l15, int l4, int BMd2,
                                              const float* bias0, const float* bias1,
                                              const float* bias2, const float* resid,
                                              float* outf, short* outb0, short* outb1,
                                              short* outb2, int N) {
#pragma unroll
  for (int mf = 0; mf < FM; ++mf) {
#pragma unroll
    for (int nf = 0; nf < NB; ++nf) {
      const int rowb = row0 + wr * BMd2 + mf * 16 + (l4 << 2);
      const int col = col0 + wc * (NB * 16) + nf * 16 + l15;
      if (MODE == 0) {
        const int which = col >> 10, nn = col & 1023;
        const int hh = nn >> 6, dd = nn & 63;
        const float bias = (which == 0 ? bias0[nn] : which == 1 ? bias1[nn] : bias2[nn]);
        short* o = (which == 0 ? outb0 : which == 1 ? outb1 : outb2);
#pragma unroll
        for (int r = 0; r < 4; ++r) {
          const int row = rowb + r;
          float val = acc[mf][nf][r] + bias;
          if (which == 0) val *= 0.18033688011112042f;  // 1/8 * log2(e)
          const int bb = row >> 11, s = row & 2047;
          const size_t dst = (((size_t)((bb << 4) + hh) << 11) + s) * HD + dd;
          o[dst] = f2bf(val);
        }
      } else {
#pragma unroll
        for (int r = 0; r < 4; ++r) {
          const int row = rowb + r;
          float val = acc[mf][nf][r];
          if (MODE == 2) {
            val += bias0[col];
            // tanh-form gelu: x - x/(e+1), e = 2^(2.302116*(x + 0.044715 x^3))
            float a = val * val;
            float c1 = fmaf(a, 0.044715f, 1.0f);
            float arg = (val * 2.302116f) * c1;
            arg = fminf(fmaxf(arg, -60.f), 60.f);
            float e = fexp2(arg);
            float gl = val - val * frcp(e + 1.0f);
            outb0[(size_t)row * N + col] = f2bf(gl);
          } else {
            val += bias0[col] + resid[(size_t)row * N + col];
            outf[(size_t)row * N + col] = val;
          }
        }
      }
    }
  }
}

// ---------------- within-XCD col-major block mapping (L2 locality)
__device__ __forceinline__ void xcd_map(int id, int nby, int nbx, int& by, int& bx) {
  const int xcd = id & 7, l = id >> 3;
  const int rpx = nby >> 3;
  by = xcd * rpx + (l % rpx);
  bx = l / rpx;
}

// ---------------- ring-2 GEMM, BM=128 x BN, 2 blocks/CU (cross-block overlap
// hides lockstep sync stalls — the QKV-proven structure, R10). BK=32 slots.
// Per slot: VMC(L)->BARRIER->ds_read->MFMA->BARRIER->STAGE(h+2).
// L = 1 + BN/128 loads/stage (uniform across all 512 threads).
// BN=256: SLOT 24KB (96KB/CU for 2 blocks). BN=128: SLOT 16KB (64KB/CU).
template <int BN, int MODE>
__global__ __launch_bounds__(512, 4) void gemm_ring2(const short* __restrict__ A,
                                                     const short* __restrict__ Bt,
                                                     const float* __restrict__ bias0,
                                                     const float* __restrict__ bias1,
                                                     const float* __restrict__ bias2,
                                                     const float* resid, float* outf,
                                                     short* outb0, short* outb1, short* outb2,
                                                     int M, int N, int K) {
  constexpr int BM = 128;
  constexpr int FM = 4;
  constexpr int NB = BN / 64;          // B frags per wave (2 or 4)
  constexpr int ASLOT = BM * 32;       // 4096 shorts = 8 KB
  constexpr int BSLOT = BN * 32;
  constexpr int SLOT = ASLOT + BSLOT;
  __shared__ short lds[2 * SLOT];

  const int tid = threadIdx.x;
  const int lane = tid & 63;
  const int wid = tid >> 6;
  const int wr = wid >> 2, wc = wid & 3;
  const int l15 = lane & 15, l4 = lane >> 4;

  int by, bx;
  xcd_map(blockIdx.x, M / BM, N / BN, by, bx);
  const int row0 = by * BM, col0 = bx * BN;

  f32x4 acc[FM][NB];
#pragma unroll
  for (int i = 0; i < FM; ++i)
#pragma unroll
    for (int j = 0; j < NB; ++j) acc[i][j] = (f32x4){0.f, 0.f, 0.f, 0.f};

  const int NH = K >> 5;

  auto STAGE = [&](int h) {
    const int k0 = h * 32;
    short* ab = lds + (h & 1) * SLOT;
    {
      const int r = tid >> 2;
      const int g = (tid & 3) ^ ((r >> 1) & 3);
      gload16(A + (size_t)(row0 + r) * K + k0 + g * 8, ab + tid * 8);
    }
    short* bb = ab + ASLOT;
#pragma unroll
    for (int s = 0; s < BN / 128; ++s) {
      const int r = s * 128 + (tid >> 2);
      const int g = (tid & 3) ^ ((r >> 1) & 3);
      gload16(Bt + (size_t)(col0 + r) * K + k0 + g * 8, bb + s * 4096 + tid * 8);
    }
  };

  bf16x8 Af[FM], Bf[NB];

  STAGE(0);
  STAGE(1);

  for (int h = 0; h < NH; ++h) {
    if (h + 1 < NH) {
      if constexpr (BN == 256) { VMC(3); } else { VMC(2); }
    } else {
      VMC(0);
    }
    BARRIER();
    {
      const short* ab = lds + (h & 1) * SLOT;
#pragma unroll
      for (int i = 0; i < FM; ++i) {
        const int R = wr * (BM / 2) + i * 16 + l15;
        Af[i] = *(const bf16x8*)(ab + (R >> 1) * 64 + (R & 1) * 32 +
                                 ((l4 ^ ((R >> 1) & 3)) << 3));
      }
      const short* bb = ab + ASLOT;
#pragma unroll
      for (int nf = 0; nf < NB; ++nf) {
        const int R = wc * (NB * 16) + nf * 16 + l15;
        Bf[nf] = *(const bf16x8*)(bb + (R >> 1) * 64 + (R & 1) * 32 +
                                  ((l4 ^ ((R >> 1) & 3)) << 3));
      }
    }
    __builtin_amdgcn_s_setprio(1);
#pragma unroll
    for (int i = 0; i < FM; ++i)
#pragma unroll
      for (int nf = 0; nf < NB; ++nf)
        acc[i][nf] = __builtin_amdgcn_mfma_f32_16x16x32_bf16(Af[i], Bf[nf], acc[i][nf], 0, 0, 0);
    __builtin_amdgcn_s_setprio(0);
    BARRIER();                       // all waves done reading slot h
    if (h + 2 < NH) STAGE(h + 2);    // safe: overwrites slot h&1
  }

  gemm_epilogue<FM, NB, MODE>(acc, row0, col0, wr, wc, l15, l4, BM / 2,
                              bias0, bias1, bias2, resid, outf, outb0, outb1, outb2, N);
}

// ---------------- flash attention, 8-wave blocks, swapped-QK^T, fixed m=0,
// counted-vmcnt double-buffer (R15-verified), bh-major grid (L2-resident K/V).
// R16: denominator via lane-local fp32 sum + permlane32_swap (removes the
// 4 ones-MFMAs/tile from the busier matrix pipe; PV = 8 MFMA/tile).
__global__ __launch_bounds__(512) void attn_swp8(const short* __restrict__ q,
                                                 const short* __restrict__ k,
                                                 const short* __restrict__ vT,
                                                 short* __restrict__ ctx) {
  __shared__ short Ks[2][4096];
  __shared__ short VTs[2][4096];
  const int tid = threadIdx.x;
  const int lane = tid & 63;
  const int wid = tid >> 6;  // 0..7
  const int hi = lane >> 5, l31 = lane & 31, l7 = lane & 7;
  const int bh = blockIdx.x, qt = blockIdx.y;
  const size_t base = (size_t)bh * SEQ * HD;
  const int q0 = qt * 256 + wid * 32;

  bf16x8 qf[4];
#pragma unroll
  for (int ks = 0; ks < 4; ++ks)
    qf[ks] = *(const bf16x8*)(q + base + (size_t)(q0 + l31) * HD + ks * 16 + hi * 8);

  f32x16 o0, o1;
#pragma unroll
  for (int r = 0; r < 16; ++r) { o0[r] = 0.f; o1[r] = 0.f; }
  float lreg = 0.f;

  const int sch = (tid & 7) ^ ((tid >> 3) & 7);

#define STAGE_AT(bi, kt)                                                            \
  {                                                                                 \
    gload16(k + base + (size_t)(kt) * 64 * HD + (size_t)(tid >> 3) * HD + sch * 8,  \
            Ks[bi] + tid * 8);                                                      \
    gload16(vT + base + (size_t)(kt) * 64 + (size_t)(tid >> 3) * SEQ + sch * 8,     \
            VTs[bi] + tid * 8);                                                     \
  }

  STAGE_AT(0, 0);
  STAGE_AT(1, 1);

  for (int kt = 0; kt < SEQ / 64; ++kt) {
    if (kt + 1 < SEQ / 64) { VMC(2); } else { VMC(0); }
    BARRIER();  // all waves' stage-kt loads landed

    const short* Kb = Ks[kt & 1];
    const short* Vb = VTs[kt & 1];

    // S^T = K . Q^T
    f32x16 s0, s1;
#pragma unroll
    for (int r = 0; r < 16; ++r) { s0[r] = 0.f; s1[r] = 0.f; }
#pragma unroll
    for (int ks = 0; ks < 4; ++ks) {
      const int ch = ((ks * 2 + hi) ^ l7) << 3;
      bf16x8 ka0 = *(const bf16x8*)(Kb + l31 * 64 + ch);
      bf16x8 ka1 = *(const bf16x8*)(Kb + (32 + l31) * 64 + ch);
      s0 = __builtin_amdgcn_mfma_f32_32x32x16_bf16(ka0, qf[ks], s0, 0, 0, 0);
      s1 = __builtin_amdgcn_mfma_f32_32x32x16_bf16(ka1, qf[ks], s1, 0, 0, 0);
    }

    // P = exp2(S) directly (fixed shift m=0; raw v_exp)
#pragma unroll
    for (int r = 0; r < 16; ++r) s0[r] = fexp2(s0[r]);
#pragma unroll
    for (int r = 0; r < 16; ++r) s1[r] = fexp2(s1[r]);

    // denominator: lane-local fp32 sum + permlane32_swap (other 32 keys of
    // this q-row live in lane+/-32 at the same column)
    {
      float rs = 0.f;
#pragma unroll
      for (int r = 0; r < 16; ++r) rs += s0[r];
#pragma unroll
      for (int r = 0; r < 16; ++r) rs += s1[r];
      int2v ss = __builtin_amdgcn_permlane32_swap(__builtin_bit_cast(int, rs),
                                                  __builtin_bit_cast(int, rs), false, false);
      lreg += __builtin_bit_cast(float, ss[0]) + __builtin_bit_cast(float, ss[1]);
    }

    // pack P -> PV B-operand fragments
    uint4v pw[4];
#pragma unroll
    for (int t = 0; t < 2; ++t) {
#pragma unroll
      for (int ks = 0; ks < 2; ++ks) {
        const f32x16& st = t ? s1 : s0;
        unsigned x0 = cvt_pk_bf16(st[8 * ks + 0], st[8 * ks + 1]);
        unsigned x1 = cvt_pk_bf16(st[8 * ks + 2], st[8 * ks + 3]);
        unsigned y0 = cvt_pk_bf16(st[8 * ks + 4], st[8 * ks + 5]);
        unsigned y1 = cvt_pk_bf16(st[8 * ks + 6], st[8 * ks + 7]);
        int2v a0 = __builtin_amdgcn_permlane32_swap((int)y0, (int)x0, false, false);
        int2v a1 = __builtin_amdgcn_permlane32_swap((int)y1, (int)x1, false, false);
        pw[t * 2 + ks] = (uint4v){(unsigned)a0[1], (unsigned)a1[1],
                                  (unsigned)a0[0], (unsigned)a1[0]};
      }
    }

    // O^T += V^T . P^T
#pragma unroll
    for (int s = 0; s < 4; ++s) {
      bf16x8 pf = __builtin_bit_cast(bf16x8, pw[s]);
      const int ch = ((s * 2 + hi) ^ l7) << 3;
      bf16x8 v0 = *(const bf16x8*)(Vb + l31 * 64 + ch);
      bf16x8 v1 = *(const bf16x8*)(Vb + (32 + l31) * 64 + ch);
      o0 = __builtin_amdgcn_mfma_f32_32x32x16_bf16(v0, pf, o0, 0, 0, 0);
      o1 = __builtin_amdgcn_mfma_f32_32x32x16_bf16(v1, pf, o1, 0, 0, 0);
    }

    BARRIER();  // all waves consumed buf[kt&1]
    if (kt + 2 < SEQ / 64) STAGE_AT(kt & 1, kt + 2);
  }
#undef STAGE_AT

  // epilogue
  const int b = bh >> 4, hh = bh & 15;
  const float inv = 1.f / lreg;
  const size_t tokoff = ((size_t)(b * SEQ + q0 + l31)) * D_MODEL + hh * HD;
#pragma unroll
  for (int r = 0; r < 16; ++r) {
    const int d = (r & 3) + 8 * (r >> 2) + 4 * hi;
    ctx[tokoff + d] = f2bf(o0[r] * inv);
    ctx[tokoff + 32 + d] = f2bf(o1[r] * inv);
  }
}

// ---------------- launcher
extern "C" void kernel_launch(void* const* d_in, const int* in_sizes, int n_in,
                              void* d_out, int out_size, void* d_ws, size_t ws_size,
                              hipStream_t stream) {
  const float* x  = (const float*)d_in[0];
  const float* Wq = (const float*)d_in[1];
  const float* bq = (const float*)d_in[2];
  const float* Wk = (const float*)d_in[3];
  const float* bk = (const float*)d_in[4];
  const float* Wv = (const float*)d_in[5];
  const float* bv = (const float*)d_in[6];
  const float* Wo = (const float*)d_in[7];
  const float* bo = (const float*)d_in[8];
  const float* g1 = (const float*)d_in[9];
  const float* b1 = (const float*)d_in[10];
  const float* g2 = (const float*)d_in[11];
  const float* b2 = (const float*)d_in[12];
  const float* W1 = (const float*)d_in[13];
  const float* bf1 = (const float*)d_in[14];
  const float* W2 = (const float*)d_in[15];
  const float* bf2 = (const float*)d_in[16];

  char* w = (char*)d_ws;
  short* WqkvT = (short*)w; w += (size_t)3072 * 1024 * 2;      // 6 MB
  short* WoT   = (short*)w; w += (size_t)1024 * 1024 * 2;      // 2 MB
  short* W1T   = (short*)w; w += (size_t)2048 * 1024 * 2;      // 4 MB
  short* W2T   = (short*)w; w += (size_t)1024 * 2048 * 2;      // 4 MB
  short* xn    = (short*)w; w += (size_t)M_TOK * 1024 * 2;     // 16 MB
  short* qb    = (short*)w; w += (size_t)M_TOK * 1024 * 2;
  short* kb    = (short*)w; w += (size_t)M_TOK * 1024 * 2;
  short* vTb   = (short*)w; w += (size_t)M_TOK * 1024 * 2;     // [BH][HD][SEQ]
  short* ctxb  = (short*)w; w += (size_t)M_TOK * 1024 * 2;
  short* xn2   = (short*)w; w += (size_t)M_TOK * 1024 * 2;
  short* hb    = (short*)w; w += (size_t)M_TOK * 2048 * 2;     // 32 MB
  short* vb    = hb;  // V row-major temp; lifetime disjoint from FFN hidden

  dim3 blk(256);

  // fused: LN1 + all weight transposes (one launch)
  prep_fused<<<dim3(M_TOK + 2048), blk, 0, stream>>>(
      x, g1, b1, xn, Wq, Wk, Wv, Wo, W1, W2, WqkvT, WoT, W1T, W2T);

  // QKV projection: ring-2 BN=256, grid 768, 2 blocks/CU
  gemm_ring2<256, 0><<<dim3(12 * 64), dim3(512), 0, stream>>>(
      xn, WqkvT, bq, bk, bv, nullptr, nullptr, qb, kb, vb, M_TOK, 3072, 1024);

  // V -> V^T (coalesced LDS-tiled transpose)
  transpose_v<<<dim3(SEQ / 64, BATCH * H_NUM), blk, 0, stream>>>(vb, vTb);

  // attention: bh in grid-x for XCD-local K/V (L2-resident per XCD)
  attn_swp8<<<dim3(64, SEQ / 256), dim3(512), 0, stream>>>(qb, kb, vTb, ctxb);

  // out proj + residual -> d_out: ring-2 BN=128, grid 512, 2 blocks/CU
  gemm_ring2<128, 1><<<dim3(8 * 64), dim3(512), 0, stream>>>(
      ctxb, WoT, bo, nullptr, nullptr, x, (float*)d_out, nullptr, nullptr, nullptr,
      M_TOK, 1024, 1024);

  // LN2
  ln_bf16<<<M_TOK, blk, 0, stream>>>((const float*)d_out, g2, b2, xn2);

  // FFN1 + GELU: ring-2 BN=256, grid 512, 2 blocks/CU
  gemm_ring2<256, 2><<<dim3(8 * 64), dim3(512), 0, stream>>>(
      xn2, W1T, bf1, nullptr, nullptr, nullptr, nullptr, hb, nullptr, nullptr,
      M_TOK, 2048, 1024);

  // FFN2 + residual (in-place on d_out): ring-2 BN=128, grid 512, 2 blocks/CU
  gemm_ring2<128, 3><<<dim3(8 * 64), dim3(512), 0, stream>>>(
      hb, W2T, bf2, nullptr, nullptr, (const float*)d_out, (float*)d_out,
      nullptr, nullptr, nullptr, M_TOK, 1024, 2048);
}

// Round 17
// 287.379 us; speedup vs baseline: 1.0111x; 1.0111x over previous
//
#include <hip/hip_runtime.h>
#include <hip/hip_bf16.h>
#include <math.h>

#define D_MODEL 1024
#define H_NUM 16
#define HD 64
#define FF_DIM 2048
#define SEQ 2048
#define BATCH 4
#define M_TOK 8192  // BATCH*SEQ

typedef __attribute__((ext_vector_type(8))) short bf16x8;
typedef __attribute__((ext_vector_type(4))) float f32x4;
typedef __attribute__((ext_vector_type(16))) float f32x16;
typedef __attribute__((ext_vector_type(4))) unsigned int uint4v;
typedef __attribute__((ext_vector_type(2))) int int2v;

__device__ __forceinline__ short f2bf(float f) {
  __hip_bfloat16 h = __float2bfloat16(f);
  return *reinterpret_cast<short*>(&h);
}

__device__ __forceinline__ void gload16(const void* g, void* l) {
  __builtin_amdgcn_global_load_lds((const __attribute__((address_space(1))) void*)g,
                                   (__attribute__((address_space(3))) void*)l, 16, 0, 0);
}

__device__ __forceinline__ unsigned cvt_pk_bf16(float lo, float hi) {
  unsigned r;
  asm("v_cvt_pk_bf16_f32 %0, %1, %2" : "=v"(r) : "v"(lo), "v"(hi));
  return r;
}

// raw v_exp_f32 (2^x). Args bounded; tiny args flush to 0 (fine for softmax).
__device__ __forceinline__ float fexp2(float x) {
  float r;
  asm("v_exp_f32 %0, %1" : "=v"(r) : "v"(x));
  return r;
}

__device__ __forceinline__ float frcp(float x) {
  float r;
  asm("v_rcp_f32 %0, %1" : "=v"(r) : "v"(x));
  return r;
}

#define BARRIER() __builtin_amdgcn_s_barrier()
#define VMC(n)                                   \
  do {                                           \
    asm volatile("s_waitcnt vmcnt(" #n ")");     \
    __builtin_amdgcn_sched_barrier(0);           \
  } while (0)

// ---------------- fused: LN1 (bid < 8192) + all weight transposes (rest)
__global__ __launch_bounds__(256) void prep_fused(
    const float* __restrict__ x, const float* __restrict__ g1,
    const float* __restrict__ b1, short* __restrict__ xn,
    const float* __restrict__ Wq, const float* __restrict__ Wk,
    const float* __restrict__ Wv, const float* __restrict__ Wo,
    const float* __restrict__ W1, const float* __restrict__ W2,
    short* __restrict__ WqkvT, short* __restrict__ WoT,
    short* __restrict__ W1T, short* __restrict__ W2T) {
  __shared__ float tile[64][65];
  if (blockIdx.x < M_TOK) {
    // LayerNorm row
    const int row = blockIdx.x;
    const int t = threadIdx.x;
    const float* xr = x + (size_t)row * D_MODEL;
    float4 v = *(const float4*)(xr + t * 4);
    float s = v.x + v.y + v.z + v.w;
    float s2 = v.x * v.x + v.y * v.y + v.z * v.z + v.w * v.w;
#pragma unroll
    for (int m = 1; m < 64; m <<= 1) { s += __shfl_xor(s, m); s2 += __shfl_xor(s2, m); }
    float* ps = &tile[0][0];
    const int wid = t >> 6, lane = t & 63;
    if (lane == 0) { ps[wid] = s; ps[wid + 4] = s2; }
    __syncthreads();
    s = ps[0] + ps[1] + ps[2] + ps[3];
    s2 = ps[4] + ps[5] + ps[6] + ps[7];
    float mu = s * (1.f / D_MODEL);
    float rstd = rsqrtf(s2 * (1.f / D_MODEL) - mu * mu + 1e-5f);
    float4 gv = *(const float4*)(g1 + t * 4);
    float4 bv = *(const float4*)(b1 + t * 4);
    short4 o;
    o.x = f2bf((v.x - mu) * rstd * gv.x + bv.x);
    o.y = f2bf((v.y - mu) * rstd * gv.y + bv.y);
    o.z = f2bf((v.z - mu) * rstd * gv.z + bv.z);
    o.w = f2bf((v.w - mu) * rstd * gv.w + bv.w);
    *(short4*)(xn + (size_t)row * D_MODEL + t * 4) = o;
    return;
  }
  const int bid = blockIdx.x - M_TOK;
  const float* src;
  short* dst;
  int K, N, t;
  if (bid < 256)       { src = Wq; dst = WqkvT;           K = 1024; N = 1024; t = bid; }
  else if (bid < 512)  { src = Wk; dst = WqkvT + 1048576; K = 1024; N = 1024; t = bid - 256; }
  else if (bid < 768)  { src = Wv; dst = WqkvT + 2097152; K = 1024; N = 1024; t = bid - 512; }
  else if (bid < 1024) { src = Wo; dst = WoT;             K = 1024; N = 1024; t = bid - 768; }
  else if (bid < 1536) { src = W1; dst = W1T;             K = 1024; N = 2048; t = bid - 1024; }
  else                 { src = W2; dst = W2T;             K = 2048; N = 1024; t = bid - 1536; }
  const int lg = (N == 2048) ? 5 : 4;
  const int ty = t >> lg, tx = t & ((1 << lg) - 1);
  const int n0 = tx * 64, k0 = ty * 64;
  const int tr = threadIdx.x >> 4;
  const int tc = (threadIdx.x & 15) * 4;
#pragma unroll
  for (int i = 0; i < 4; ++i) {
    int kr = tr + i * 16;
    float4 v = *(const float4*)(src + (size_t)(k0 + kr) * N + n0 + tc);
    tile[kr][tc] = v.x; tile[kr][tc + 1] = v.y; tile[kr][tc + 2] = v.z; tile[kr][tc + 3] = v.w;
  }
  __syncthreads();
#pragma unroll
  for (int i = 0; i < 4; ++i) {
    int r = tr + i * 16;
    short4 o;
    o.x = f2bf(tile[tc][r]);
    o.y = f2bf(tile[tc + 1][r]);
    o.z = f2bf(tile[tc + 2][r]);
    o.w = f2bf(tile[tc + 3][r]);
    *(short4*)(dst + (size_t)(n0 + r) * K + k0 + tc) = o;
  }
}

// ---------------- V transpose: [BH][SEQ][HD] bf16 -> [BH][HD][SEQ]
__global__ __launch_bounds__(256) void transpose_v(const short* __restrict__ src,
                                                   short* __restrict__ dst) {
  __shared__ short t[64][72];
  const int s0 = blockIdx.x * 64;
  const size_t b = (size_t)blockIdx.y * SEQ * HD;
  const int r = threadIdx.x >> 2;          // seq row 0..63
  const int c = (threadIdx.x & 3) * 16;    // d col 0/16/32/48
  *(bf16x8*)&t[r][c] = *(const bf16x8*)(src + b + (size_t)(s0 + r) * HD + c);
  *(bf16x8*)&t[r][c + 8] = *(const bf16x8*)(src + b + (size_t)(s0 + r) * HD + c + 8);
  __syncthreads();
  const int d = threadIdx.x >> 2;          // d row 0..63
  const int cc = (threadIdx.x & 3) * 16;   // seq chunk
  bf16x8 o0, o1;
#pragma unroll
  for (int i = 0; i < 8; ++i) o0[i] = t[cc + i][d];
#pragma unroll
  for (int i = 0; i < 8; ++i) o1[i] = t[cc + 8 + i][d];
  *(bf16x8*)(dst + b + (size_t)d * SEQ + s0 + cc) = o0;
  *(bf16x8*)(dst + b + (size_t)d * SEQ + s0 + cc + 8) = o1;
}

// ---------------- LayerNorm fp32 [rows][1024] -> bf16, one block per row
__global__ __launch_bounds__(256) void ln_bf16(const float* __restrict__ x,
                                               const float* __restrict__ g,
                                               const float* __restrict__ b,
                                               short* __restrict__ out) {
  const int row = blockIdx.x;
  const int t = threadIdx.x;
  const float* xr = x + (size_t)row * D_MODEL;
  float4 v = *(const float4*)(xr + t * 4);
  float s = v.x + v.y + v.z + v.w;
  float s2 = v.x * v.x + v.y * v.y + v.z * v.z + v.w * v.w;
#pragma unroll
  for (int m = 1; m < 64; m <<= 1) { s += __shfl_xor(s, m); s2 += __shfl_xor(s2, m); }
  __shared__ float ps[8];
  const int wid = t >> 6, lane = t & 63;
  if (lane == 0) { ps[wid] = s; ps[wid + 4] = s2; }
  __syncthreads();
  s = ps[0] + ps[1] + ps[2] + ps[3];
  s2 = ps[4] + ps[5] + ps[6] + ps[7];
  float mu = s * (1.f / D_MODEL);
  float rstd = rsqrtf(s2 * (1.f / D_MODEL) - mu * mu + 1e-5f);
  float4 gv = *(const float4*)(g + t * 4);
  float4 bv = *(const float4*)(b + t * 4);
  short4 o;
  o.x = f2bf((v.x - mu) * rstd * gv.x + bv.x);
  o.y = f2bf((v.y - mu) * rstd * gv.y + bv.y);
  o.z = f2bf((v.z - mu) * rstd * gv.z + bv.z);
  o.w = f2bf((v.w - mu) * rstd * gv.w + bv.w);
  *(short4*)(out + (size_t)row * D_MODEL + t * 4) = o;
}

// ---------------- shared GEMM epilogue (NB = B frags per wave)
template <int FM, int NB, int MODE>
__device__ __forceinline__ void gemm_epilogue(f32x4 (&acc)[FM][NB], int row0, int col0,
                                              int wr, int wc, int l15, int l4, int BMd2,
                                              const float* bias0, const float* bias1,
                                              const float* bias2, const float* resid,
                                              float* outf, short* outb0, short* outb1,
                                              short* outb2, int N) {
#pragma unroll
  for (int mf = 0; mf < FM; ++mf) {
#pragma unroll
    for (int nf = 0; nf < NB; ++nf) {
      const int rowb = row0 + wr * BMd2 + mf * 16 + (l4 << 2);
      const int col = col0 + wc * (NB * 16) + nf * 16 + l15;
      if (MODE == 0) {
        const int which = col >> 10, nn = col & 1023;
        const int hh = nn >> 6, dd = nn & 63;
        const float bias = (which == 0 ? bias0[nn] : which == 1 ? bias1[nn] : bias2[nn]);
        short* o = (which == 0 ? outb0 : which == 1 ? outb1 : outb2);
#pragma unroll
        for (int r = 0; r < 4; ++r) {
          const int row = rowb + r;
          float val = acc[mf][nf][r] + bias;
          if (which == 0) val *= 0.18033688011112042f;  // 1/8 * log2(e)
          const int bb = row >> 11, s = row & 2047;
          const size_t dst = (((size_t)((bb << 4) + hh) << 11) + s) * HD + dd;
          o[dst] = f2bf(val);
        }
      } else {
#pragma unroll
        for (int r = 0; r < 4; ++r) {
          const int row = rowb + r;
          float val = acc[mf][nf][r];
          if (MODE == 2) {
            val += bias0[col];
            // tanh-form gelu: x - x/(e+1), e = 2^(2.302116*(x + 0.044715 x^3))
            float a = val * val;
            float c1 = fmaf(a, 0.044715f, 1.0f);
            float arg = (val * 2.302116f) * c1;
            arg = fminf(fmaxf(arg, -60.f), 60.f);
            float e = fexp2(arg);
            float gl = val - val * frcp(e + 1.0f);
            outb0[(size_t)row * N + col] = f2bf(gl);
          } else {
            val += bias0[col] + resid[(size_t)row * N + col];
            outf[(size_t)row * N + col] = val;
          }
        }
      }
    }
  }
}

// ---------------- within-XCD col-major block mapping (L2 locality)
__device__ __forceinline__ void xcd_map(int id, int nby, int nbx, int& by, int& bx) {
  const int xcd = id & 7, l = id >> 3;
  const int rpx = nby >> 3;
  by = xcd * rpx + (l % rpx);
  bx = l / rpx;
}

// ---------------- ring-2 GEMM, BM=128 x BN, 2 blocks/CU (R16-verified:
// cross-block overlap beats lockstep 1-blk/CU schedules by ~10us aggregate).
// Per slot: VMC(L)->BARRIER->ds_read->MFMA->BARRIER->STAGE(h+2).
template <int BN, int MODE>
__global__ __launch_bounds__(512, 4) void gemm_ring2(const short* __restrict__ A,
                                                     const short* __restrict__ Bt,
                                                     const float* __restrict__ bias0,
                                                     const float* __restrict__ bias1,
                                                     const float* __restrict__ bias2,
                                                     const float* resid, float* outf,
                                                     short* outb0, short* outb1, short* outb2,
                                                     int M, int N, int K) {
  constexpr int BM = 128;
  constexpr int FM = 4;
  constexpr int NB = BN / 64;          // B frags per wave (2 or 4)
  constexpr int ASLOT = BM * 32;       // 8 KB
  constexpr int BSLOT = BN * 32;
  constexpr int SLOT = ASLOT + BSLOT;
  __shared__ short lds[2 * SLOT];

  const int tid = threadIdx.x;
  const int lane = tid & 63;
  const int wid = tid >> 6;
  const int wr = wid >> 2, wc = wid & 3;
  const int l15 = lane & 15, l4 = lane >> 4;

  int by, bx;
  xcd_map(blockIdx.x, M / BM, N / BN, by, bx);
  const int row0 = by * BM, col0 = bx * BN;

  f32x4 acc[FM][NB];
#pragma unroll
  for (int i = 0; i < FM; ++i)
#pragma unroll
    for (int j = 0; j < NB; ++j) acc[i][j] = (f32x4){0.f, 0.f, 0.f, 0.f};

  const int NH = K >> 5;

  auto STAGE = [&](int h) {
    const int k0 = h * 32;
    short* ab = lds + (h & 1) * SLOT;
    {
      const int r = tid >> 2;
      const int g = (tid & 3) ^ ((r >> 1) & 3);
      gload16(A + (size_t)(row0 + r) * K + k0 + g * 8, ab + tid * 8);
    }
    short* bb = ab + ASLOT;
#pragma unroll
    for (int s = 0; s < BN / 128; ++s) {
      const int r = s * 128 + (tid >> 2);
      const int g = (tid & 3) ^ ((r >> 1) & 3);
      gload16(Bt + (size_t)(col0 + r) * K + k0 + g * 8, bb + s * 4096 + tid * 8);
    }
  };

  bf16x8 Af[FM], Bf[NB];

  STAGE(0);
  STAGE(1);

  for (int h = 0; h < NH; ++h) {
    if (h + 1 < NH) {
      if constexpr (BN == 256) { VMC(3); } else { VMC(2); }
    } else {
      VMC(0);
    }
    BARRIER();
    {
      const short* ab = lds + (h & 1) * SLOT;
#pragma unroll
      for (int i = 0; i < FM; ++i) {
        const int R = wr * (BM / 2) + i * 16 + l15;
        Af[i] = *(const bf16x8*)(ab + (R >> 1) * 64 + (R & 1) * 32 +
                                 ((l4 ^ ((R >> 1) & 3)) << 3));
      }
      const short* bb = ab + ASLOT;
#pragma unroll
      for (int nf = 0; nf < NB; ++nf) {
        const int R = wc * (NB * 16) + nf * 16 + l15;
        Bf[nf] = *(const bf16x8*)(bb + (R >> 1) * 64 + (R & 1) * 32 +
                                  ((l4 ^ ((R >> 1) & 3)) << 3));
      }
    }
    __builtin_amdgcn_s_setprio(1);
#pragma unroll
    for (int i = 0; i < FM; ++i)
#pragma unroll
      for (int nf = 0; nf < NB; ++nf)
        acc[i][nf] = __builtin_amdgcn_mfma_f32_16x16x32_bf16(Af[i], Bf[nf], acc[i][nf], 0, 0, 0);
    __builtin_amdgcn_s_setprio(0);
    BARRIER();                       // all waves done reading slot h
    if (h + 2 < NH) STAGE(h + 2);    // safe: overwrites slot h&1
  }

  gemm_epilogue<FM, NB, MODE>(acc, row0, col0, wr, wc, l15, l4, BM / 2,
                              bias0, bias1, bias2, resid, outf, outb0, outb1, outb2, N);
}

// ---------------- flash attention (R15-measured-best body): 8-wave blocks,
// swapped-QK^T, fixed m=0, ones-MFMA denominator (o2 rides the matrix pipe as
// free ILP — R16 proved the lane-local VALU sum chain is worse), counted-vmcnt
// double-buffer, bh-major grid (L2-resident K/V per XCD).
__global__ __launch_bounds__(512) void attn_swp8(const short* __restrict__ q,
                                                 const short* __restrict__ k,
                                                 const short* __restrict__ vT,
                                                 short* __restrict__ ctx) {
  __shared__ short Ks[2][4096];
  __shared__ short VTs[2][4096];
  const int tid = threadIdx.x;
  const int lane = tid & 63;
  const int wid = tid >> 6;  // 0..7
  const int hi = lane >> 5, l31 = lane & 31, l7 = lane & 7;
  const int bh = blockIdx.x, qt = blockIdx.y;
  const size_t base = (size_t)bh * SEQ * HD;
  const int q0 = qt * 256 + wid * 32;

  bf16x8 qf[4];
#pragma unroll
  for (int ks = 0; ks < 4; ++ks)
    qf[ks] = *(const bf16x8*)(q + base + (size_t)(q0 + l31) * HD + ks * 16 + hi * 8);

  bf16x8 onesv;
#pragma unroll
  for (int i = 0; i < 8; ++i) onesv[i] = (short)0x3F80;  // bf16 1.0

  f32x16 o0, o1, o2;
#pragma unroll
  for (int r = 0; r < 16; ++r) { o0[r] = 0.f; o1[r] = 0.f; o2[r] = 0.f; }

  const int sch = (tid & 7) ^ ((tid >> 3) & 7);

#define STAGE_AT(bi, kt)                                                            \
  {                                                                                 \
    gload16(k + base + (size_t)(kt) * 64 * HD + (size_t)(tid >> 3) * HD + sch * 8,  \
            Ks[bi] + tid * 8);                                                      \
    gload16(vT + base + (size_t)(kt) * 64 + (size_t)(tid >> 3) * SEQ + sch * 8,     \
            VTs[bi] + tid * 8);                                                     \
  }

  STAGE_AT(0, 0);
  STAGE_AT(1, 1);

  for (int kt = 0; kt < SEQ / 64; ++kt) {
    if (kt + 1 < SEQ / 64) { VMC(2); } else { VMC(0); }
    BARRIER();  // all waves' stage-kt loads landed

    const short* Kb = Ks[kt & 1];
    const short* Vb = VTs[kt & 1];

    // S^T = K . Q^T
    f32x16 s0, s1;
#pragma unroll
    for (int r = 0; r < 16; ++r) { s0[r] = 0.f; s1[r] = 0.f; }
#pragma unroll
    for (int ks = 0; ks < 4; ++ks) {
      const int ch = ((ks * 2 + hi) ^ l7) << 3;
      bf16x8 ka0 = *(const bf16x8*)(Kb + l31 * 64 + ch);
      bf16x8 ka1 = *(const bf16x8*)(Kb + (32 + l31) * 64 + ch);
      s0 = __builtin_amdgcn_mfma_f32_32x32x16_bf16(ka0, qf[ks], s0, 0, 0, 0);
      s1 = __builtin_amdgcn_mfma_f32_32x32x16_bf16(ka1, qf[ks], s1, 0, 0, 0);
    }

    // P = exp2(S) directly (fixed shift m=0; raw v_exp)
#pragma unroll
    for (int r = 0; r < 16; ++r) s0[r] = fexp2(s0[r]);
#pragma unroll
    for (int r = 0; r < 16; ++r) s1[r] = fexp2(s1[r]);

    // pack P -> PV B-operand fragments
    uint4v pw[4];
#pragma unroll
    for (int t = 0; t < 2; ++t) {
#pragma unroll
      for (int ks = 0; ks < 2; ++ks) {
        const f32x16& st = t ? s1 : s0;
        unsigned x0 = cvt_pk_bf16(st[8 * ks + 0], st[8 * ks + 1]);
        unsigned x1 = cvt_pk_bf16(st[8 * ks + 2], st[8 * ks + 3]);
        unsigned y0 = cvt_pk_bf16(st[8 * ks + 4], st[8 * ks + 5]);
        unsigned y1 = cvt_pk_bf16(st[8 * ks + 6], st[8 * ks + 7]);
        int2v a0 = __builtin_amdgcn_permlane32_swap((int)y0, (int)x0, false, false);
        int2v a1 = __builtin_amdgcn_permlane32_swap((int)y1, (int)x1, false, false);
        pw[t * 2 + ks] = (uint4v){(unsigned)a0[1], (unsigned)a1[1],
                                  (unsigned)a0[0], (unsigned)a1[0]};
      }
    }

    // O^T += V^T . P^T ; o2 += ones . P^T (row-sum on MFMA pipe)
#pragma unroll
    for (int s = 0; s < 4; ++s) {
      bf16x8 pf = __builtin_bit_cast(bf16x8, pw[s]);
      const int ch = ((s * 2 + hi) ^ l7) << 3;
      bf16x8 v0 = *(const bf16x8*)(Vb + l31 * 64 + ch);
      bf16x8 v1 = *(const bf16x8*)(Vb + (32 + l31) * 64 + ch);
      o0 = __builtin_amdgcn_mfma_f32_32x32x16_bf16(v0, pf, o0, 0, 0, 0);
      o1 = __builtin_amdgcn_mfma_f32_32x32x16_bf16(v1, pf, o1, 0, 0, 0);
      o2 = __builtin_amdgcn_mfma_f32_32x32x16_bf16(onesv, pf, o2, 0, 0, 0);
    }

    BARRIER();  // all waves consumed buf[kt&1]
    if (kt + 2 < SEQ / 64) STAGE_AT(kt & 1, kt + 2);
  }
#undef STAGE_AT

  // epilogue
  const int b = bh >> 4, hh = bh & 15;
  const float inv = 1.f / o2[0];
  const size_t tokoff = ((size_t)(b * SEQ + q0 + l31)) * D_MODEL + hh * HD;
#pragma unroll
  for (int r = 0; r < 16; ++r) {
    const int d = (r & 3) + 8 * (r >> 2) + 4 * hi;
    ctx[tokoff + d] = f2bf(o0[r] * inv);
    ctx[tokoff + 32 + d] = f2bf(o1[r] * inv);
  }
}

// ---------------- launcher
extern "C" void kernel_launch(void* const* d_in, const int* in_sizes, int n_in,
                              void* d_out, int out_size, void* d_ws, size_t ws_size,
                              hipStream_t stream) {
  const float* x  = (const float*)d_in[0];
  const float* Wq = (const float*)d_in[1];
  const float* bq = (const float*)d_in[2];
  const float* Wk = (const float*)d_in[3];
  const float* bk = (const float*)d_in[4];
  const float* Wv = (const float*)d_in[5];
  const float* bv = (const float*)d_in[6];
  const float* Wo = (const float*)d_in[7];
  const float* bo = (const float*)d_in[8];
  const float* g1 = (const float*)d_in[9];
  const float* b1 = (const float*)d_in[10];
  const float* g2 = (const float*)d_in[11];
  const float* b2 = (const float*)d_in[12];
  const float* W1 = (const float*)d_in[13];
  const float* bf1 = (const float*)d_in[14];
  const float* W2 = (const float*)d_in[15];
  const float* bf2 = (const float*)d_in[16];

  char* w = (char*)d_ws;
  short* WqkvT = (short*)w; w += (size_t)3072 * 1024 * 2;      // 6 MB
  short* WoT   = (short*)w; w += (size_t)1024 * 1024 * 2;      // 2 MB
  short* W1T   = (short*)w; w += (size_t)2048 * 1024 * 2;      // 4 MB
  short* W2T   = (short*)w; w += (size_t)1024 * 2048 * 2;      // 4 MB
  short* xn    = (short*)w; w += (size_t)M_TOK * 1024 * 2;     // 16 MB
  short* qb    = (short*)w; w += (size_t)M_TOK * 1024 * 2;
  short* kb    = (short*)w; w += (size_t)M_TOK * 1024 * 2;
  short* vTb   = (short*)w; w += (size_t)M_TOK * 1024 * 2;     // [BH][HD][SEQ]
  short* ctxb  = (short*)w; w += (size_t)M_TOK * 1024 * 2;
  short* xn2   = (short*)w; w += (size_t)M_TOK * 1024 * 2;
  short* hb    = (short*)w; w += (size_t)M_TOK * 2048 * 2;     // 32 MB
  short* vb    = hb;  // V row-major temp; lifetime disjoint from FFN hidden

  dim3 blk(256);

  // fused: LN1 + all weight transposes (one launch)
  prep_fused<<<dim3(M_TOK + 2048), blk, 0, stream>>>(
      x, g1, b1, xn, Wq, Wk, Wv, Wo, W1, W2, WqkvT, WoT, W1T, W2T);

  // QKV projection: ring-2 BN=256, grid 768, 2 blocks/CU
  gemm_ring2<256, 0><<<dim3(12 * 64), dim3(512), 0, stream>>>(
      xn, WqkvT, bq, bk, bv, nullptr, nullptr, qb, kb, vb, M_TOK, 3072, 1024);

  // V -> V^T (coalesced LDS-tiled transpose)
  transpose_v<<<dim3(SEQ / 64, BATCH * H_NUM), blk, 0, stream>>>(vb, vTb);

  // attention: bh in grid-x for XCD-local K/V (L2-resident per XCD)
  attn_swp8<<<dim3(64, SEQ / 256), dim3(512), 0, stream>>>(qb, kb, vTb, ctxb);

  // out proj + residual -> d_out: ring-2 BN=128, grid 512, 2 blocks/CU
  gemm_ring2<128, 1><<<dim3(8 * 64), dim3(512), 0, stream>>>(
      ctxb, WoT, bo, nullptr, nullptr, x, (float*)d_out, nullptr, nullptr, nullptr,
      M_TOK, 1024, 1024);

  // LN2
  ln_bf16<<<M_TOK, blk, 0, stream>>>((const float*)d_out, g2, b2, xn2);

  // FFN1 + GELU: ring-2 BN=256, grid 512, 2 blocks/CU
  gemm_ring2<256, 2><<<dim3(8 * 64), dim3(512), 0, stream>>>(
      xn2, W1T, bf1, nullptr, nullptr, nullptr, nullptr, hb, nullptr, nullptr,
      M_TOK, 2048, 1024);

  // FFN2 + residual (in-place on d_out): ring-2 BN=128, grid 512, 2 blocks/CU
  gemm_ring2<128, 3><<<dim3(8 * 64), dim3(512), 0, stream>>>(
      hb, W2T, bf2, nullptr, nullptr, (const float*)d_out, (float*)d_out,
      nullptr, nullptr, nullptr, M_TOK, 1024, 2048);
}